// Round 4
// baseline (14.863 us; speedup 1.0000x reference)
//
#include <hip/hip_runtime.h>

// Problem constants (match reference)
static constexpr int Bn = 4;     // batch
static constexpr int Kn = 128;   // proposals per image
static constexpr int Gn = 128;   // gt boxes per image

// Output layout: concatenated flat in return order, all as float32
static constexpr int OFF_ROIS   = 0;
static constexpr int OFF_OBJ    = Bn * Kn * 4;               // 2048
static constexpr int OFF_DELTAS = OFF_OBJ + Bn * Kn * 1024;  // 526336
static constexpr int OFF_RANKS  = OFF_DELTAS + Bn * Kn * 4;  // 528384
static constexpr int OFF_SPAT   = OFF_RANKS + Bn * Kn;       // 528896

// Window constants, computed in f32 exactly as jnp does
static constexpr float W0  = 128.0f / 1023.0f;
static constexpr float W2  = 895.0f / 1023.0f;
static constexpr float WSY = W2 - W0;

// rounded_f32(inter/uni) >= 0.5  <=>  inter/uni >= 0.5 - 2^-26 (exact reals)
// (0.5 is representable; the midpoint 0.5-2^-26 ties to even = 0.5.)
// (double)inter >= CTH*(double)uni is EXACT: 26-bit * 24-bit fits in f64.
static constexpr double CTH = 0.5 - 1.4901161193847656e-08;  // 0.5 - 2^-26

__device__ __forceinline__ int cvt_coord(float v, float shift, float scl,
                                         float dscale, float dshift) {
    float t = __fdiv_rn(__fsub_rn(v, shift), scl);
    float u = __fadd_rn(__fmul_rn(t, dscale), dshift);
    return (int)rintf(u);  // round half to even, matches jnp.round
}

// One block per PAIR of output rows. Hot loop computes only the existence bit
// pos(r) = (max_j rounded(iou) >= 0.5) via the exact division-free f64 test.
// Argmax (exact __fdiv_rn, first-occurrence) is recomputed only for the <=2
// rows this block owns, one wave per owned row.
__global__ __launch_bounds__(256)
void k_fused(const float* __restrict__ props, const float* __restrict__ feat,
             const float* __restrict__ gtb, const int* __restrict__ gtr,
             float* __restrict__ out)
{
    const int blk  = blockIdx.x;       // 0..255
    const int b    = blk >> 6;         // 64 blocks per image
    const int d0   = (blk & 63) << 1;  // first dest of this block's pair
    const int t    = threadIdx.x;
    const int lane = t & 63, wave = t >> 6;

    __shared__ float4 sg[Gn];
    __shared__ float  sag[Gn];
    __shared__ float4 spp[Kn];
    __shared__ unsigned long long sbal[4];
    __shared__ int    s_src[2];
    __shared__ int4   sbox[2];

    // stage gt boxes (+areas) and proposals
    if (t < 128) {
        float4 g = reinterpret_cast<const float4*>(gtb)[b * Gn + t];
        sg[t]  = g;
        sag[t] = __fmul_rn(__fsub_rn(g.z, g.x), __fsub_rn(g.w, g.y));
        spp[t] = reinterpret_cast<const float4*>(props)[b * Kn + t];
    }
    __syncthreads();

    // existence loop: row i = t&127, gt half jbase = (t>>7)*64
    const int i     = t & 127;
    const int jbase = (t >> 7) << 6;
    float4 p  = spp[i];
    float  ap = __fmul_rn(__fsub_rn(p.z, p.x), __fsub_rn(p.w, p.y));
    // wave-uniform base into gtb for this half -> scalar loads
    const float* gq = gtb + (size_t)(b * Gn + __builtin_amdgcn_readfirstlane(jbase)) * 4;
    bool found = false;
    #pragma unroll 4
    for (int jj = 0; jj < 64; ++jj) {
        float qx = gq[4 * jj + 0], qy = gq[4 * jj + 1];
        float qz = gq[4 * jj + 2], qw = gq[4 * jj + 3];
        float yy1 = fmaxf(p.x, qx), xx1 = fmaxf(p.y, qy);
        float yy2 = fminf(p.z, qz), xx2 = fminf(p.w, qw);
        float ih  = fmaxf(__fsub_rn(yy2, yy1), 0.0f);
        float iw  = fmaxf(__fsub_rn(xx2, xx1), 0.0f);
        float inter = __fmul_rn(iw, ih);
        float uni   = __fsub_rn(__fadd_rn(ap, sag[jbase + jj]), inter);
        found |= ((double)inter >= CTH * (double)uni);
    }
    unsigned long long bal = __ballot(found);
    if (lane == 0) sbal[wave] = bal;
    __syncthreads();

    // phase 3: waves 0,1 each resolve one owned dest row
    if (wave < 2) {
        const unsigned long long m01 = sbal[0] | sbal[2];  // pos bits rows 0-63
        const unsigned long long m23 = sbal[1] | sbal[3];  // pos bits rows 64-127
        const int nPos   = __popcll(m01) + __popcll(m23);
        const int target = d0 + wave;
        const unsigned long long lm = (lane == 63) ? ~0ull >> 1 : ((1ull << lane) - 1ull);
        // wait: (1ull<<63)-1 is fine; simpler mask below
        const unsigned long long lmask = (1ull << lane) - 1ull;  // ok for lane<64? lane=63 -> (1<<63)-1 correct
        (void)lm;
        // row r1 = lane
        const int pos1 = (int)((m01 >> lane) & 1ull);
        const int pb1  = __popcll(m01 & lmask);
        const int dst1 = pos1 ? pb1 : nPos + (lane - pb1);
        // row r2 = lane + 64
        const int pos2 = (int)((m23 >> lane) & 1ull);
        const int pb2  = __popcll(m01) + __popcll(m23 & lmask);
        const int dst2 = pos2 ? pb2 : nPos + (lane + 64 - pb2);

        const unsigned long long b1 = __ballot(dst1 == target);
        const unsigned long long b2 = __ballot(dst2 == target);
        int src, spos;
        if (b1) { int l = __ffsll((long long)b1) - 1; src = l;      spos = (int)((m01 >> l) & 1ull); }
        else    { int l = __ffsll((long long)b2) - 1; src = 64 + l; spos = (int)((m23 >> l) & 1ull); }

        // exact argmax over j (first occurrence), 2 j's per lane
        float4 ps  = spp[src];
        float  aps = __fmul_rn(__fsub_rn(ps.z, ps.x), __fsub_rn(ps.w, ps.y));
        float v[2]; int jj2[2] = { lane, lane + 64 };
        #pragma unroll
        for (int h = 0; h < 2; ++h) {
            const int j = jj2[h];
            float4 q  = sg[j];
            float yy1 = fmaxf(ps.x, q.x), xx1 = fmaxf(ps.y, q.y);
            float yy2 = fminf(ps.z, q.z), xx2 = fminf(ps.w, q.w);
            float ih  = fmaxf(__fsub_rn(yy2, yy1), 0.0f);
            float iw  = fmaxf(__fsub_rn(xx2, xx1), 0.0f);
            float inter = __fmul_rn(iw, ih);
            float uni   = __fsub_rn(__fadd_rn(aps, sag[j]), inter);
            v[h] = __fdiv_rn(inter, uni);
        }
        float bv = v[0]; int bj = lane;
        if (v[1] > bv) { bv = v[1]; bj = lane + 64; }   // strict: low j wins ties
        #pragma unroll
        for (int off = 1; off < 64; off <<= 1) {
            float ov = __shfl_xor(bv, off);
            int   oj = __shfl_xor(bj, off);
            if (ov > bv || (ov == bv && oj < bj)) { bv = ov; bj = oj; }
        }

        if (lane == 0) {
            const bool pos = (spos != 0);
            float4 agt = sg[bj];
            float h  = ps.z - ps.x, w  = ps.w - ps.y;
            float cy = ps.x + 0.5f * h, cx = ps.y + 0.5f * w;
            float gh = agt.z - agt.x, gw = agt.w - agt.y;
            float gcy = agt.x + 0.5f * gh, gcx = agt.y + 0.5f * gw;
            float d0f = ((gcy - cy) / h) / 0.1f;
            float d1f = ((gcx - cx) / w) / 0.1f;
            float d2f = logf(gh / h) / 0.2f;
            float d3f = logf(gw / w) / 0.2f;
            float4 deltas = pos ? make_float4(d0f, d1f, d2f, d3f)
                                : make_float4(0.f, 0.f, 0.f, 0.f);
            float4 rg = pos ? agt : make_float4(0.f, 0.f, 0.f, 0.f);

            int ib0 = cvt_coord(rg.x, W0, WSY, 479.0f, 0.0f);
            int ib1 = cvt_coord(rg.y, 0.0f, 1.0f, 639.0f, 0.0f);
            int ib2 = cvt_coord(rg.z, W0, WSY, 479.0f, 1.0f);
            int ib3 = cvt_coord(rg.w, 0.0f, 1.0f, 639.0f, 1.0f);
            int area = (ib2 - ib0) * (ib3 - ib1);
            if (!(area > 0)) { ib0 = 0; ib1 = 0; ib2 = 0; ib3 = 0; }

            const int o = b * Kn + target;
            reinterpret_cast<float4*>(out + OFF_ROIS)[o]   = ps;
            reinterpret_cast<float4*>(out + OFF_DELTAS)[o] = deltas;
            out[OFF_RANKS + o] = (float)(pos ? gtr[b * Gn + bj] : 0);
            s_src[wave] = src;
            sbox[wave]  = make_int4(ib0, ib1, ib2, ib3);
        }
    }
    __syncthreads();

    #pragma unroll
    for (int slot = 0; slot < 2; ++slot) {
        const int  o   = b * Kn + d0 + slot;
        const int  src = s_src[slot];
        const int4 bb  = sbox[slot];

        // obj gather: one 1024-float row, float4 per thread
        const float4* srow = reinterpret_cast<const float4*>(feat) + (b * Gn + src) * 256;
        reinterpret_cast<float4*>(out + OFF_OBJ)[o * 256 + t] = srow[t];

        // spatial feature: 4 consecutive pixels per thread (one float4 store)
        const int p0      = t * 4;
        const int row     = p0 >> 5;       // 32 cols
        const int colBase = p0 & 31;
        float4 sp = make_float4(0.f, 0.f, 0.f, 0.f);
        if (row >= 4 && row < 28) {
            const int r   = row - 4;
            const int ys0 = 20 * r + 9, ys1 = ys0 + 1;
            const int fy  = (int)((bb.x < ys0) & (ys0 < bb.z)) +
                            (int)((bb.x < ys1) & (ys1 < bb.z));
            if (fy) {
                float vv[4];
                #pragma unroll
                for (int q = 0; q < 4; ++q) {
                    const int c   = colBase + q;
                    const int xs0 = 20 * c + 9, xs1 = xs0 + 1;
                    const int fx  = (int)((bb.y < xs0) & (xs0 < bb.w)) +
                                    (int)((bb.y < xs1) & (xs1 < bb.w));
                    vv[q] = 0.25f * (float)(fy * fx);
                }
                sp = make_float4(vv[0], vv[1], vv[2], vv[3]);
            }
        }
        reinterpret_cast<float4*>(out + OFF_SPAT)[o * 256 + t] = sp;
    }
}

extern "C" void kernel_launch(void* const* d_in, const int* in_sizes, int n_in,
                              void* d_out, int out_size, void* d_ws, size_t ws_size,
                              hipStream_t stream) {
    (void)in_sizes; (void)n_in; (void)out_size; (void)d_ws; (void)ws_size;
    const float* props = (const float*)d_in[0];   // (B,G,4) f32
    const float* feat  = (const float*)d_in[1];   // (B,G,1,1,1024) f32
    const float* gtb   = (const float*)d_in[2];   // (B,G,4) f32
    const int*   gtr   = (const int*)d_in[3];     // (B,G) i32
    float* out = (float*)d_out;

    k_fused<<<(Bn * Kn) / 2, 256, 0, stream>>>(props, feat, gtb, gtr, out);
}

// Round 5
// 13.273 us; speedup vs baseline: 1.1198x; 1.1198x over previous
//
#include <hip/hip_runtime.h>

// Problem constants (match reference)
static constexpr int Bn = 4;     // batch
static constexpr int Kn = 128;   // proposals per image
static constexpr int Gn = 128;   // gt boxes per image

// Output layout: concatenated flat in return order, all as float32
static constexpr int OFF_ROIS   = 0;
static constexpr int OFF_OBJ    = Bn * Kn * 4;               // 2048
static constexpr int OFF_DELTAS = OFF_OBJ + Bn * Kn * 1024;  // 526336
static constexpr int OFF_RANKS  = OFF_DELTAS + Bn * Kn * 4;  // 528384
static constexpr int OFF_SPAT   = OFF_RANKS + Bn * Kn;       // 528896

// Window constants, computed in f32 exactly as jnp does:
// _WIN = ([128,0,896,1024]-[0,0,1,1])/1023  (f32)
static constexpr float W0  = 128.0f / 1023.0f;   // win y1
static constexpr float W2  = 895.0f / 1023.0f;   // win y2
static constexpr float WSY = W2 - W0;            // y scale
// x: shift 0, scale 1.0 exactly

__device__ __forceinline__ int cvt_coord(float v, float shift, float scl,
                                         float dscale, float dshift) {
    // match np:  round(((v - shift)/scl) * dscale + dshift)  in f32, no FMA
    float t = __fdiv_rn(__fsub_rn(v, shift), scl);
    float u = __fadd_rn(__fmul_rn(t, dscale), dshift);
    return (int)rintf(u);  // round half to even, matches jnp.round
}

// One block per PAIR of output rows (o0 = 2*blk, o1 = o0+1), 256 blocks total
// (1 block/CU). Each block redundantly recomputes the per-image assignment
// (256 threads x 64-iter IoU half-rows), the two unique owner threads write
// the small per-row outputs and publish src + int-box; all 256 threads then
// emit the two 1024-float obj rows and the two 32x32 spatial features.
//
// R4 lesson: keep argmax fused in the hot loop (thread-parallel, off the
// critical path). Division-free f64 test + serial owned-row argmax regressed.
__global__ __launch_bounds__(256)
void k_fused(const float* __restrict__ props, const float* __restrict__ feat,
             const float* __restrict__ gtb, const int* __restrict__ gtr,
             float* __restrict__ out)
{
    const int blk  = blockIdx.x;       // 0..255
    const int b    = blk >> 6;         // 64 blocks per image
    const int d0   = (blk & 63) << 1;  // first dest of this block's pair
    const int t    = threadIdx.x;

    __shared__ float4 sg[Gn];
    __shared__ float  sag[Gn];
    __shared__ float4 spp[Kn];
    __shared__ float  sbest[256];
    __shared__ int    sbj[256];
    __shared__ int    scnt[2];
    __shared__ int    s_src[2];
    __shared__ int4   sbox[2];

    // stage gt boxes (+areas) and proposals
    if (t < 128) {
        float4 g = reinterpret_cast<const float4*>(gtb)[b * Gn + t];
        sg[t]  = g;
        sag[t] = __fmul_rn(__fsub_rn(g.z, g.x), __fsub_rn(g.w, g.y));
        spp[t] = reinterpret_cast<const float4*>(props)[b * Kn + t];
    }
    __syncthreads();

    // IoU: proposal i = t&127, gt half jbase = (t>>7)*64
    const int i     = t & 127;
    const int jbase = (t >> 7) << 6;
    float4 p  = spp[i];
    float  ap = __fmul_rn(__fsub_rn(p.z, p.x), __fsub_rn(p.w, p.y));
    float best = -1.0f;
    int   bj   = jbase;
    #pragma unroll 4
    for (int jj = 0; jj < 64; ++jj) {
        const int j = jbase + jj;
        float4 q  = sg[j];
        float yy1 = fmaxf(p.x, q.x), xx1 = fmaxf(p.y, q.y);
        float yy2 = fminf(p.z, q.z), xx2 = fminf(p.w, q.w);
        float ih  = fmaxf(__fsub_rn(yy2, yy1), 0.0f);
        float iw  = fmaxf(__fsub_rn(xx2, xx1), 0.0f);
        float inter = __fmul_rn(iw, ih);
        float uni   = __fsub_rn(__fadd_rn(ap, sag[j]), inter);
        float iou   = __fdiv_rn(inter, uni);
        if (iou > best) { best = iou; bj = j; }
    }
    sbest[t] = best;
    sbj[t]   = bj;
    __syncthreads();

    // combine halves (first-occurrence argmax: half0 has lower j, so b0>=b1 keeps it)
    bool pos = false;
    int  bjf = 0;
    if (t < 128) {
        float b0 = sbest[t], b1 = sbest[t + 128];
        bjf = (b0 >= b1) ? sbj[t] : sbj[t + 128];
        pos = (fmaxf(b0, b1) >= 0.5f);
    }

    // stable partition: positives first (original order), then negatives
    unsigned long long m = __ballot(pos);   // waves 2,3: m == 0, harmless
    const int lane = t & 63, wave = t >> 6;
    const int prefix = __popcll(m & ((1ull << lane) - 1ull));
    if (lane == 0 && wave < 2) scnt[wave] = __popcll(m);
    __syncthreads();

    if (t < 128) {
        const int total     = scnt[0] + scnt[1];
        const int posBefore = prefix + (wave ? scnt[0] : 0);
        const int dst_i     = pos ? posBefore : (total + (t - posBefore));
        const int slot      = dst_i - d0;
        if (slot == 0 || slot == 1) {
            s_src[slot] = t;

            // refinement deltas on ORIGINAL proposal/assigned-gt
            float4 agt = sg[bjf];
            float h  = p.z - p.x, w  = p.w - p.y;
            float cy = p.x + 0.5f * h, cx = p.y + 0.5f * w;
            float gh = agt.z - agt.x, gw = agt.w - agt.y;
            float gcy = agt.x + 0.5f * gh, gcx = agt.y + 0.5f * gw;
            float d0f = ((gcy - cy) / h) / 0.1f;
            float d1f = ((gcx - cx) / w) / 0.1f;
            float d2f = logf(gh / h) / 0.2f;
            float d3f = logf(gw / w) / 0.2f;
            float4 deltas = pos ? make_float4(d0f, d1f, d2f, d3f)
                                : make_float4(0.f, 0.f, 0.f, 0.f);
            float4 rg = pos ? agt : make_float4(0.f, 0.f, 0.f, 0.f);

            // spatial box -> integer pixel box (f32 sequence matches np)
            int ib0 = cvt_coord(rg.x, W0, WSY, 479.0f, 0.0f);
            int ib1 = cvt_coord(rg.y, 0.0f, 1.0f, 639.0f, 0.0f);
            int ib2 = cvt_coord(rg.z, W0, WSY, 479.0f, 1.0f);
            int ib3 = cvt_coord(rg.w, 0.0f, 1.0f, 639.0f, 1.0f);
            int area = (ib2 - ib0) * (ib3 - ib1);
            if (!(area > 0)) { ib0 = 0; ib1 = 0; ib2 = 0; ib3 = 0; }
            sbox[slot] = make_int4(ib0, ib1, ib2, ib3);

            const int o = b * Kn + dst_i;
            reinterpret_cast<float4*>(out + OFF_ROIS)[o]   = p;
            reinterpret_cast<float4*>(out + OFF_DELTAS)[o] = deltas;
            out[OFF_RANKS + o] = (float)(pos ? gtr[b * Gn + bjf] : 0);
        }
    }
    __syncthreads();

    #pragma unroll
    for (int slot = 0; slot < 2; ++slot) {
        const int  o   = b * Kn + d0 + slot;
        const int  src = s_src[slot];
        const int4 bb  = sbox[slot];

        // obj gather: one 1024-float row, float4 per thread
        const float4* srow = reinterpret_cast<const float4*>(feat) + (b * Gn + src) * 256;
        reinterpret_cast<float4*>(out + OFF_OBJ)[o * 256 + t] = srow[t];

        // spatial feature: 4 consecutive pixels per thread (one float4 store)
        const int p0      = t * 4;
        const int row     = p0 >> 5;       // 32 cols
        const int colBase = p0 & 31;
        float4 sp = make_float4(0.f, 0.f, 0.f, 0.f);
        if (row >= 4 && row < 28) {
            const int r   = row - 4;
            const int ys0 = 20 * r + 9, ys1 = ys0 + 1;
            const int fy  = (int)((bb.x < ys0) & (ys0 < bb.z)) +
                            (int)((bb.x < ys1) & (ys1 < bb.z));
            if (fy) {
                float v[4];
                #pragma unroll
                for (int q = 0; q < 4; ++q) {
                    const int c   = colBase + q;
                    const int xs0 = 20 * c + 9, xs1 = xs0 + 1;
                    const int fx  = (int)((bb.y < xs0) & (xs0 < bb.w)) +
                                    (int)((bb.y < xs1) & (xs1 < bb.w));
                    v[q] = 0.25f * (float)(fy * fx);
                }
                sp = make_float4(v[0], v[1], v[2], v[3]);
            }
        }
        reinterpret_cast<float4*>(out + OFF_SPAT)[o * 256 + t] = sp;
    }
}

extern "C" void kernel_launch(void* const* d_in, const int* in_sizes, int n_in,
                              void* d_out, int out_size, void* d_ws, size_t ws_size,
                              hipStream_t stream) {
    (void)in_sizes; (void)n_in; (void)out_size; (void)d_ws; (void)ws_size;
    const float* props = (const float*)d_in[0];   // (B,G,4) f32
    const float* feat  = (const float*)d_in[1];   // (B,G,1,1,1024) f32
    const float* gtb   = (const float*)d_in[2];   // (B,G,4) f32
    const int*   gtr   = (const int*)d_in[3];     // (B,G) i32
    float* out = (float*)d_out;

    k_fused<<<(Bn * Kn) / 2, 256, 0, stream>>>(props, feat, gtb, gtr, out);
}